// Round 7
// baseline (125.087 us; speedup 1.0000x reference)
//
#include <hip/hip_runtime.h>
#include <hip/hip_cooperative_groups.h>
#include <cstdint>
#include <cstddef>

namespace cg = cooperative_groups;

#define NQ 900
#define NC 91
#define NFLAT (NQ * NC)        // 81900
#define NF4 (NFLAT / 4)        // 20475
#define BS 8
#define PRE_TOPK 10000
#define TOPK 100
#define IOU_THR 0.7f
#define NT 1024
#define NWAVES 16
#define NCAND 256              // bitmap candidate count (global top-256)
#define HEADZ 2.55078125f      // head cut: z >= 2.5508 (E=440/batch, sig=21)
#define NSL 8                  // slices per batch; grid = 64 blocks
#define LCAP 128               // keys per slice (E=55, +9.9 sigma)
#define HEADCAP (NSL * LCAP)   // 1024

// ws layout (fill is unconditional -> using ws costs nothing):
//   CNT u32[64]  at 0        counts ALWAYS written each launch (poison-safe)
//   KEY u64[64][LCAP] at 256
#define CNT_OFF 0
#define KEY_OFF 256
#define WS_REQ ((size_t)KEY_OFF + (size_t)BS * NSL * LCAP * 8)

// sigmoid monotone => order on raw logit z == order on prob.
__device__ __forceinline__ unsigned int mono_u(float z) {
    unsigned int b = __float_as_uint(z);
    return b ^ ((unsigned int)((int)b >> 31) | 0x80000000u);
}
__device__ __forceinline__ float inv_mono(unsigned int u) {
    unsigned int b = (u & 0x80000000u) ? (u ^ 0x80000000u) : ~u;
    return __uint_as_float(b);
}
// 49-bit distinct key == lax.top_k order (score desc, idx asc)
__device__ __forceinline__ unsigned long long make_key(unsigned int u, int i) {
    return ((unsigned long long)u << 17) | (unsigned long long)(131071 - i);
}

// ---------------- single cooperative kernel ----------------
// Phase A (64 blocks): head filter of one (batch,slice) -> keys+count to ws
// grid.sync()
// Phase B (blocks 0..7): gather -> rank-scatter top-256 -> bitmap NMS -> out
extern "C" __global__ __launch_bounds__(NT)
void k_all(const float* __restrict__ logits,
           const float* __restrict__ pboxes,
           const float* __restrict__ tsizes,
           float* __restrict__ out,
           void* __restrict__ ws,
           const int forceBad) {
    __shared__ unsigned long long sPool[PRE_TOPK];    // 80 KB (fallback; sweep cand)
    __shared__ unsigned long long sSup[1024];         // 8 KB suppression bitmap
    __shared__ float4 sBox[NQ];                       // 14.4 KB scaled xyxy boxes
    __shared__ unsigned long long sHead[HEADCAP];     // 8 KB head candidates
    __shared__ unsigned long long sTop[NCAND];        // 2 KB sorted top-256
    __shared__ float4 sOB[NCAND];                     // 4 KB offset obox
    __shared__ float sOar[NCAND];                     // 1 KB obox area
    __shared__ unsigned long long sKeepW[4];
    __shared__ float sKx1[TOPK], sKy1[TOPK], sKx2[TOPK], sKy2[TOPK], sKa[TOPK];
    __shared__ float sFirst[6];
    __shared__ float sRedF[NWAVES];
    __shared__ int sWTot[NWAVES], sWSuf[NWAVES];
    __shared__ int sCntRaw[NSL], sCnt[NSL], sPre[NSL];
    __shared__ int sFlag, sKept, sPos, sNK, sHC, sSwCnt;
    __shared__ float sBmax;
    unsigned long long* const cand = sPool;           // sweep-phase union

    const int tid = threadIdx.x;
    const int wid = tid >> 6, lane = tid & 63;
    const unsigned long long laneLT = (1ULL << lane) - 1ULL;
    unsigned int* const cntw = (unsigned int*)((char*)ws + CNT_OFF);
    unsigned long long* const keyw = (unsigned long long*)((char*)ws + KEY_OFF);

    if (!forceBad) {
        // ======== Phase A: sweep (all 64 blocks) ========
        const int bb = blockIdx.x >> 3, ss = blockIdx.x & 7;
        const float* lgs = logits + (size_t)bb * NFLAT;
        const int j0 = (ss * NF4) / NSL, j1 = ((ss + 1) * NF4) / NSL; // width<=2560
        if (tid == 0) sSwCnt = 0;
        __syncthreads();
        {
            float4 v[3]; bool hv[3];
            #pragma unroll
            for (int u = 0; u < 3; ++u) {
                const int j = j0 + tid + u * NT;
                hv[u] = (j < j1);
                v[u] = ((const float4*)lgs)[hv[u] ? j : (NF4 - 1)];
            }
            #pragma unroll
            for (int u = 0; u < 3; ++u) {
                const int j = j0 + tid + u * NT;
                const bool c0 = hv[u] && (v[u].x >= HEADZ);
                const bool c1 = hv[u] && (v[u].y >= HEADZ);
                const bool c2 = hv[u] && (v[u].z >= HEADZ);
                const bool c3 = hv[u] && (v[u].w >= HEADZ);
                const unsigned long long m0 = __ballot(c0), m1 = __ballot(c1),
                                         m2 = __ballot(c2), m3 = __ballot(c3);
                const int p0 = __popcll(m0), p1 = __popcll(m1), p2 = __popcll(m2);
                const int n = p0 + p1 + p2 + __popcll(m3);
                if (n == 0) continue;
                int base = 0;
                if (lane == 0) base = atomicAdd(&sSwCnt, n);
                base = __shfl(base, 0, 64);
                if (c0) { const int o = base + __popcll(m0 & laneLT);
                          if (o < LCAP) cand[o] = make_key(mono_u(v[u].x), 4 * j); }
                if (c1) { const int o = base + p0 + __popcll(m1 & laneLT);
                          if (o < LCAP) cand[o] = make_key(mono_u(v[u].y), 4 * j + 1); }
                if (c2) { const int o = base + p0 + p1 + __popcll(m2 & laneLT);
                          if (o < LCAP) cand[o] = make_key(mono_u(v[u].z), 4 * j + 2); }
                if (c3) { const int o = base + p0 + p1 + p2 + __popcll(m3 & laneLT);
                          if (o < LCAP) cand[o] = make_key(mono_u(v[u].w), 4 * j + 3); }
            }
        }
        __syncthreads();
        {
            const int n = sSwCnt;
            if (tid == 0) cntw[blockIdx.x] = (unsigned int)n;   // ALWAYS written
            const int nw = n < LCAP ? n : LCAP;
            if (tid < nw) keyw[(size_t)blockIdx.x * LCAP + tid] = cand[tid];
        }
        __threadfence();
        cg::this_grid().sync();
        if (blockIdx.x >= BS) return;
    }

    // ======== Phase B: tail (blocks 0..7, one per batch) ========
    const int b = blockIdx.x;
    const float* lg = logits + (size_t)b * NFLAT;
    const float* bx = pboxes + (size_t)b * NQ * 4;
    const float img_h = tsizes[b * 2 + 0], img_w = tsizes[b * 2 + 1];

    // ---- P0: state, slice counts, box staging, register bmax ----
    sHead[tid] = 0ULL;                                // pad for unrolled rank
    if (tid == 0) { sFlag = forceBad; sKept = 0; sPos = 0; sNK = 0; sHC = 0; }
    if (tid < NSL && !forceBad) sCntRaw[tid] = (int)cntw[b * NSL + tid];
    {
        float lmax = -3.4e38f;
        if (tid < NQ) {
            const float4 bb = ((const float4*)bx)[tid];
            float4 sb;
            sb.x = (bb.x - 0.5f * bb.z) * img_w;
            sb.y = (bb.y - 0.5f * bb.w) * img_h;
            sb.z = (bb.x + 0.5f * bb.z) * img_w;
            sb.w = (bb.y + 0.5f * bb.w) * img_h;
            sBox[tid] = sb;
            lmax = fmaxf(fmaxf(sb.x, sb.y), fmaxf(sb.z, sb.w));
        }
        for (int off = 32; off >= 1; off >>= 1)
            lmax = fmaxf(lmax, __shfl_xor(lmax, off, 64));
        if (lane == 0) sRedF[wid] = lmax;
    }
    __syncthreads();

    // ---- P1a: wave 0 prefix-scan of slice counts; validity checks ----
    if (wid == 0) {
        const int craw = (lane < NSL && !forceBad) ? sCntRaw[lane] : 0;
        if (lane < NSL && craw > LCAP) sFlag = 1;     // slice overflow
        const int c = craw < LCAP ? craw : LCAP;
        int v = c;
        #pragma unroll
        for (int off = 1; off < NSL; off <<= 1) {
            const int o = __shfl(v, lane - off, 64);
            if (lane >= off) v += o;
        }
        if (lane < NSL) { sPre[lane] = v - c; sCnt[lane] = c; }
        if (lane == NSL - 1) {
            sHC = v;                                  // total head count (<=1024)
            if (v < NCAND) sFlag = 1;                 // must cover top-256
        }
    }
    __syncthreads();
    int bad = sFlag;

    // ---- P1b: gather slice keys -> contiguous sHead (2 waves per slice) ----
    if (!bad) {
        const int sl = wid >> 1, i = ((wid & 1) << 6) + lane;
        if (i < sCnt[sl])
            sHead[sPre[sl] + i] = keyw[(size_t)(b * NSL + sl) * LCAP + i];
    }
    __syncthreads();

    // ---- P2: rank-scatter -> exact sorted global top-256 ----
    if (!bad) {
        const int hc = sHC;
        if (tid < hc) {
            const unsigned long long k = sHead[tid];
            int r = 0;
            const int hp = (hc + 7) & ~7;
            for (int q = 0; q < hp; q += 8) {     // 8 independent broadcast reads
                #pragma unroll
                for (int u = 0; u < 8; ++u) r += (sHead[q + u] > k) ? 1 : 0;
            }
            if (r < NCAND) sTop[r] = k;
        }
    }
    __syncthreads();

    // ---- P3: candidate prep (fold 16-way bmax here) ----
    if (!bad && tid < NCAND) {
        float mm = sRedF[0];
        #pragma unroll
        for (int q = 1; q < NWAVES; ++q) mm = fmaxf(mm, sRedF[q]);
        const unsigned long long k = sTop[tid];
        const int i = 131071 - (int)(k & 0x1FFFFULL);
        const int bi = i / NC, l = i - bi * NC;
        const float4 sb = sBox[bi];
        const float o = (float)l * (mm + 1.0f);
        float4 ob;
        ob.x = sb.x + o; ob.y = sb.y + o; ob.z = sb.z + o; ob.w = sb.w + o;
        sOB[tid] = ob;
        sOar[tid] = (ob.z - ob.x) * (ob.w - ob.y);
    }
    __syncthreads();

    // ---- P4: suppression bitmap via ballot (conflict-free layout) ----
    if (!bad) {
        const int w = wid & 3;
        const int r0 = (wid >> 2) << 6;
        const int cj = (w << 6) + lane;
        const float4 cb = sOB[cj];
        const float car = sOar[cj];
        for (int t = 0; t < 64; ++t) {
            const int i = r0 + t;
            const float4 rb = sOB[i];            // broadcast
            const float ra = sOar[i];
            float iw = fminf(rb.z, cb.z) - fmaxf(rb.x, cb.x);
            float ih = fminf(rb.w, cb.w) - fmaxf(rb.y, cb.y);
            iw = fmaxf(iw, 0.f); ih = fmaxf(ih, 0.f);
            const float inter = iw * ih;
            const bool sup = inter > IOU_THR * (ra + car - inter);
            const unsigned long long bits = __ballot(sup);
            if (lane == 0) sSup[(i << 2) | w] = bits;
        }
    }
    __syncthreads();

    // ---- P5: bitmap scan (wave 0) ----
    if (!bad && wid == 0) {
        unsigned long long live = (lane < 4) ? ~0ULL : 0ULL;   // C == 256
        unsigned long long keepW = 0ULL;
        int kept = 0;
        const int myw = lane & 3;
        for (int ch = 0; ch < 4 && kept < TOPK; ++ch) {
            unsigned long long cur = __shfl(live, ch, 64);
            unsigned long long acc = 0ULL;
            #pragma unroll 8
            for (int bit = 0; bit < 64; ++bit) {
                const int i = (ch << 6) | bit;
                const unsigned long long rowC = sSup[(i << 2) | ch];
                const unsigned long long rowM = sSup[(i << 2) | myw];
                if ((cur >> bit) & 1ULL) {
                    cur &= ~rowC;
                    acc |= rowM;
                    if (lane == ch) keepW |= 1ULL << bit;
                }
            }
            if (lane < 4) live &= ~acc;
            int c = __popcll(keepW);
            for (int off = 32; off >= 1; off >>= 1) c += __shfl_xor(c, off, 64);
            kept = c;
        }
        if (lane < 4) sKeepW[lane] = keepW;
        if (lane == 0) sNK = kept;
    }
    __syncthreads();
    if (tid == 0 && sFlag == 0) {
        if (sNK < TOPK) sFlag = 1; else sKept = TOPK;
    }
    __syncthreads();
    bad = sFlag;

    // ---- P6: rank -> direct outputs ----
    if (!bad && tid < NCAND) {
        const int w = tid >> 6;
        const unsigned long long m = sKeepW[w];
        if ((m >> (tid & 63)) & 1ULL) {
            int rank = __popcll(m & ((1ULL << (tid & 63)) - 1ULL));
            for (int ww = 0; ww < w; ++ww) rank += __popcll(sKeepW[ww]);
            if (rank < TOPK) {
                const unsigned long long k = sTop[tid];
                const int i = 131071 - (int)(k & 0x1FFFFULL);
                const int bi = i / NC, l = i - bi * NC;
                const float4 sb = sBox[bi];
                const float z = inv_mono((unsigned int)(k >> 17));
                const int oi = b * TOPK + rank;
                out[oi] = 1.0f / (1.0f + expf(-z));
                out[BS * TOPK + oi] = (float)l;
                out[2 * BS * TOPK + oi * 4 + 0] = sb.x;
                out[2 * BS * TOPK + oi * 4 + 1] = sb.y;
                out[2 * BS * TOPK + oi * 4 + 2] = sb.z;
                out[2 * BS * TOPK + oi * 4 + 3] = sb.w;
            }
        }
    }

    if (bad) {
        // ======== exact fallback (logits only; never taken for sane inputs) ========
        unsigned long long lo = 0, hi = (1ULL << 49) - 1;
        while (lo < hi) {
            const unsigned long long mid = lo + ((hi - lo + 1) >> 1);
            int c = 0;
            for (int j = tid; j < NF4; j += NT) {
                const float4 v = ((const float4*)lg)[j];
                const float zv[4] = { v.x, v.y, v.z, v.w };
                #pragma unroll
                for (int q = 0; q < 4; ++q)
                    c += (make_key(mono_u(zv[q]), 4 * j + q) >= mid) ? 1 : 0;
            }
            for (int off = 32; off >= 1; off >>= 1) c += __shfl_xor(c, off, 64);
            if (lane == 0) sWTot[wid] = c;
            __syncthreads();
            if (tid == 0) {
                int a = 0;
                for (int w = 0; w < NWAVES; ++w) a += sWTot[w];
                sPos = a;
            }
            __syncthreads();
            if (sPos >= PRE_TOPK) lo = mid; else hi = mid - 1;
            __syncthreads();
        }
        if (tid == 0) sPos = 0;
        __syncthreads();
        for (int j = tid; j < NF4; j += NT) {
            const float4 v = ((const float4*)lg)[j];
            const float zv[4] = { v.x, v.y, v.z, v.w };
            #pragma unroll
            for (int q = 0; q < 4; ++q) {
                const unsigned long long k = make_key(mono_u(zv[q]), 4 * j + q);
                const bool cnd = k >= lo;         // exactly 10000 (keys distinct)
                const unsigned long long mask = __ballot(cnd);
                int pos = 0;
                if (lane == 0 && mask) pos = atomicAdd(&sPos, __popcll(mask));
                pos = __shfl(pos, 0, 64);
                if (cnd) sPool[pos + __popcll(mask & laneLT)] = k;
            }
        }
        __syncthreads();
        {   // full rank sort of 10000 (slow, correct)
            unsigned long long stash[10]; int spp[10]; int ns = 0;
            for (int p = tid; p < PRE_TOPK; p += NT) {
                const unsigned long long k = sPool[p];
                int r = 0;
                for (int q = 0; q < PRE_TOPK; ++q) r += (sPool[q] > k) ? 1 : 0;
                if (ns < 10) { stash[ns] = k; spp[ns] = r; ++ns; }
            }
            __syncthreads();
            for (int q = 0; q < ns; ++q) sPool[spp[q]] = stash[q];
        }
        __syncthreads();
        float lmax = -3.4e38f;
        for (int p = tid; p < PRE_TOPK; p += NT) {
            const int i = 131071 - (int)(sPool[p] & 0x1FFFFULL);
            const float4 sb = sBox[i / NC];
            lmax = fmaxf(lmax, fmaxf(fmaxf(sb.x, sb.y), fmaxf(sb.z, sb.w)));
        }
        for (int off = 32; off >= 1; off >>= 1)
            lmax = fmaxf(lmax, __shfl_xor(lmax, off, 64));
        if (lane == 0) sRedF[wid] = lmax;
        __syncthreads();
        if (tid == 0) {
            float mm = sRedF[0];
            for (int k2 = 1; k2 < NWAVES; ++k2) mm = fmaxf(mm, sRedF[k2]);
            sBmax = mm;
        }
        __syncthreads();
        const float offc = sBmax + 1.0f;
        if (wid == 0) {
            int kept = 0;
            for (int base = 0; base < PRE_TOPK && kept < TOPK; base += 64) {
                const int c = base + lane;
                const bool valid = c < PRE_TOPK;
                const unsigned long long k = valid ? sPool[c] : 0ULL;
                const int i = valid ? (131071 - (int)(k & 0x1FFFFULL)) : 0;
                const int bi = i / NC, l = i - bi * NC;
                const float4 sb = sBox[bi];
                const float o = (float)l * offc;
                const float ox1 = sb.x + o, oy1 = sb.y + o, ox2 = sb.z + o, oy2 = sb.w + o;
                const float ar = (ox2 - ox1) * (oy2 - oy1);
                bool alive = valid;
                for (int jj = 0; jj < kept; ++jj) {
                    float iw = fminf(sKx2[jj], ox2) - fmaxf(sKx1[jj], ox1);
                    float ih = fminf(sKy2[jj], oy2) - fmaxf(sKy1[jj], oy1);
                    iw = fmaxf(iw, 0.f); ih = fmaxf(ih, 0.f);
                    const float inter = iw * ih;
                    if (inter > IOU_THR * (sKa[jj] + ar - inter)) alive = false;
                }
                unsigned long long mask = __ballot(alive);
                while (mask != 0ULL && kept < TOPK) {
                    const int s = __ffsll((unsigned long long)mask) - 1;
                    const float px1 = __shfl(ox1, s, 64);
                    const float py1 = __shfl(oy1, s, 64);
                    const float px2 = __shfl(ox2, s, 64);
                    const float py2 = __shfl(oy2, s, 64);
                    const float pa  = __shfl(ar,  s, 64);
                    if (lane == s) {
                        sKx1[kept] = ox1; sKy1[kept] = oy1; sKx2[kept] = ox2;
                        sKy2[kept] = oy2; sKa[kept] = ar;
                        const int oi = b * TOPK + kept;
                        const float z = inv_mono((unsigned int)(k >> 17));
                        const float sc = 1.0f / (1.0f + expf(-z));
                        out[oi] = sc;
                        out[BS * TOPK + oi] = (float)l;
                        out[2 * BS * TOPK + oi * 4 + 0] = sb.x;
                        out[2 * BS * TOPK + oi * 4 + 1] = sb.y;
                        out[2 * BS * TOPK + oi * 4 + 2] = sb.z;
                        out[2 * BS * TOPK + oi * 4 + 3] = sb.w;
                        if (kept == 0) { sFirst[0] = sc; sFirst[1] = (float)l;
                                         sFirst[2] = sb.x; sFirst[3] = sb.y;
                                         sFirst[4] = sb.z; sFirst[5] = sb.w; }
                    }
                    ++kept;
                    if (alive) {
                        float iw = fminf(px2, ox2) - fmaxf(px1, ox1);
                        float ih = fminf(py2, oy2) - fmaxf(py1, oy1);
                        iw = fmaxf(iw, 0.f); ih = fmaxf(ih, 0.f);
                        const float inter = iw * ih;
                        if (inter > IOU_THR * (pa + ar - inter)) alive = false;
                    }
                    mask = __ballot(alive);
                }
            }
            if (lane == 0) sKept = kept;
        }
        __syncthreads();
    }

    // exhaustion: ref's argmax over all -inf -> index 0 -> replicate row 0
    for (int t = sKept + tid; t < TOPK; t += NT) {
        const int oi = b * TOPK + t;
        out[oi] = sFirst[0];
        out[BS * TOPK + oi] = sFirst[1];
        out[2 * BS * TOPK + oi * 4 + 0] = sFirst[2];
        out[2 * BS * TOPK + oi * 4 + 1] = sFirst[3];
        out[2 * BS * TOPK + oi * 4 + 2] = sFirst[4];
        out[2 * BS * TOPK + oi * 4 + 3] = sFirst[5];
    }
}

extern "C" void kernel_launch(void* const* d_in, const int* in_sizes, int n_in,
                              void* d_out, int out_size, void* d_ws, size_t ws_size,
                              hipStream_t stream) {
    const float* logits = (const float*)d_in[0];   // (8, 900, 91) fp32
    const float* pboxes = (const float*)d_in[1];   // (8, 900, 4) fp32
    const float* ts     = (const float*)d_in[2];   // (8, 2) fp32
    float* outp = (float*)d_out;
    void* wsp = d_ws;
    if (ws_size >= WS_REQ) {
        int forceBad = 0;
        void* args[] = { (void*)&logits, (void*)&pboxes, (void*)&ts,
                         (void*)&outp, (void*)&wsp, (void*)&forceBad };
        hipLaunchCooperativeKernel((const void*)k_all, dim3(NSL * BS), dim3(NT),
                                   args, 0, stream);
    } else {
        // no workspace: exact fallback path; skips sweep AND grid sync (safe
        // for a normal launch)
        hipLaunchKernelGGL(k_all, dim3(BS), dim3(NT), 0, stream,
                           logits, pboxes, ts, outp, wsp, 1);
    }
}

// Round 8
// 79.357 us; speedup vs baseline: 1.5762x; 1.5762x over previous
//
#include <hip/hip_runtime.h>
#include <cstdint>
#include <cstddef>

#define NQ 900
#define NC 91
#define NFLAT (NQ * NC)        // 81900
#define NF4 (NFLAT / 4)        // 20475
#define BS 8
#define PRE_TOPK 10000
#define TOPK 100
#define IOU_THR 0.7f
#define NT 1024
#define NWAVES 16
#define NCAND 128              // bitmap candidate count (global top-128)
#define HEADZ 2.75f            // head cut: z >= 2.75 (E=244/batch, sig=15.6)
#define NSL 32                 // sweep slices per batch
#define SLCAP 32               // keys per slice slot (E=7.6, +8.8 sigma)
#define HEADCAP (NSL * SLCAP)  // 1024 (LDS bound; realistic hc ~244)
#define K1T 256                // sweep block size

// ws layout: counts always rewritten each launch -> no memset needed (poison-safe)
#define CNT_OFF 0                                   // u32 [BS][NSL]
#define KEY_OFF 1024                                // u64 [BS][NSL][SLCAP]
#define WS_REQ ((size_t)KEY_OFF + (size_t)BS * NSL * SLCAP * 8)

// sigmoid monotone => order on raw logit z == order on prob.
__device__ __forceinline__ unsigned int mono_u(float z) {
    unsigned int b = __float_as_uint(z);
    return b ^ ((unsigned int)((int)b >> 31) | 0x80000000u);
}
__device__ __forceinline__ float inv_mono(unsigned int u) {
    unsigned int b = (u & 0x80000000u) ? (u ^ 0x80000000u) : ~u;
    return __uint_as_float(b);
}
// 49-bit distinct key == lax.top_k order (score desc, idx asc)
__device__ __forceinline__ unsigned long long make_key(unsigned int u, int i) {
    return ((unsigned long long)u << 17) | (unsigned long long)(131071 - i);
}

// ---------------- k_sweep: 256 blocks, head filter -> per-slice slots ----------------
extern "C" __global__ __launch_bounds__(K1T)
void k_sweep(const float* __restrict__ logits, void* __restrict__ ws) {
    __shared__ unsigned long long keys[SLCAP];
    __shared__ int cnt;
    const int sl = blockIdx.x, b = blockIdx.y;
    const int tid = threadIdx.x, lane = tid & 63;
    const unsigned long long laneLT = (1ULL << lane) - 1ULL;
    if (tid == 0) cnt = 0;
    __syncthreads();
    const float* lg = logits + (size_t)b * NFLAT;
    const int j0 = (sl * NF4) / NSL, j1 = ((sl + 1) * NF4) / NSL;
    for (int j = j0 + tid; j < j1; j += K1T) {
        const float4 v = ((const float4*)lg)[j];
        const bool c0 = v.x >= HEADZ, c1 = v.y >= HEADZ,
                   c2 = v.z >= HEADZ, c3 = v.w >= HEADZ;
        const unsigned long long m0 = __ballot(c0), m1 = __ballot(c1),
                                 m2 = __ballot(c2), m3 = __ballot(c3);
        const int p0 = __popcll(m0), p1 = __popcll(m1), p2 = __popcll(m2);
        const int n = p0 + p1 + p2 + __popcll(m3);
        int base = 0;
        if (lane == 0 && n) base = atomicAdd(&cnt, n);
        base = __shfl(base, 0, 64);
        if (c0) { const int o = base + __popcll(m0 & laneLT);
                  if (o < SLCAP) keys[o] = make_key(mono_u(v.x), 4 * j); }
        if (c1) { const int o = base + p0 + __popcll(m1 & laneLT);
                  if (o < SLCAP) keys[o] = make_key(mono_u(v.y), 4 * j + 1); }
        if (c2) { const int o = base + p0 + p1 + __popcll(m2 & laneLT);
                  if (o < SLCAP) keys[o] = make_key(mono_u(v.z), 4 * j + 2); }
        if (c3) { const int o = base + p0 + p1 + p2 + __popcll(m3 & laneLT);
                  if (o < SLCAP) keys[o] = make_key(mono_u(v.w), 4 * j + 3); }
    }
    __syncthreads();
    const int n = cnt;
    unsigned long long* kw = (unsigned long long*)((char*)ws + KEY_OFF)
                             + ((size_t)b * NSL + sl) * SLCAP;
    const int nw = n < SLCAP ? n : SLCAP;
    if (tid < nw) kw[tid] = keys[tid];
    // count ALWAYS written (no memset needed); n > SLCAP signals overflow -> fallback
    if (tid == 0) ((unsigned int*)((char*)ws + CNT_OFF))[b * NSL + sl] = (unsigned int)n;
}

// ---------------- k_tail: 8 blocks, gather -> rank -> bitmap NMS ----------------
extern "C" __global__ __launch_bounds__(NT)
void k_tail(const float* __restrict__ logits,
            const float* __restrict__ pboxes,
            const float* __restrict__ tsizes,
            float* __restrict__ out,
            const void* __restrict__ ws,
            const int forceBad) {
    __shared__ unsigned long long sPool[PRE_TOPK];    // 80 KB (fallback only)
    __shared__ unsigned long long sSup[2 * NCAND];    // 2 KB suppression bitmap
    __shared__ float4 sBox[NQ];                       // 14.4 KB scaled xyxy boxes
    __shared__ unsigned long long sHead[HEADCAP];     // 8 KB head candidates
    __shared__ unsigned long long sTop[NCAND];        // 1 KB sorted top-128
    __shared__ float4 sOB[NCAND];                     // 2 KB offset obox
    __shared__ float sOar[NCAND];                     // 0.5 KB obox area
    __shared__ unsigned long long sKeepW[2];
    __shared__ float sKx1[TOPK], sKy1[TOPK], sKx2[TOPK], sKy2[TOPK], sKa[TOPK];
    __shared__ float sFirst[6];
    __shared__ float sRedF[NWAVES];
    __shared__ int sWTot[NWAVES], sWSuf[NWAVES];
    __shared__ int sCnt[NSL], sPre[NSL];
    __shared__ int sFlag, sKept, sPos, sNK, sHC;
    __shared__ float sBmax;

    const int b = blockIdx.x;
    const int tid = threadIdx.x;
    const int wid = tid >> 6, lane = tid & 63;
    const float* lg = logits + (size_t)b * NFLAT;
    const float* bx = pboxes + (size_t)b * NQ * 4;
    const float img_h = tsizes[b * 2 + 0], img_w = tsizes[b * 2 + 1];
    const unsigned long long laneLT = (1ULL << lane) - 1ULL;

    // ---- P0: state, slice counts, box staging, register bmax ----
    sHead[tid] = 0ULL;                                // pad for unrolled rank
    if (tid == 0) { sFlag = forceBad; sKept = 0; sPos = 0; sNK = 0; sHC = 0; }
    if (tid < NSL && !forceBad)
        sCnt[tid] = (int)((const unsigned int*)((const char*)ws + CNT_OFF))[b * NSL + tid];
    {
        float lmax = -3.4e38f;
        if (tid < NQ) {
            const float4 bb = ((const float4*)bx)[tid];
            float4 sb;
            sb.x = (bb.x - 0.5f * bb.z) * img_w;
            sb.y = (bb.y - 0.5f * bb.w) * img_h;
            sb.z = (bb.x + 0.5f * bb.z) * img_w;
            sb.w = (bb.y + 0.5f * bb.w) * img_h;
            sBox[tid] = sb;
            lmax = fmaxf(fmaxf(sb.x, sb.y), fmaxf(sb.z, sb.w));
        }
        for (int off = 32; off >= 1; off >>= 1)
            lmax = fmaxf(lmax, __shfl_xor(lmax, off, 64));
        if (lane == 0) sRedF[wid] = lmax;
    }
    __syncthreads();

    // ---- P1a: wave 0 prefix-scan of slice counts; validity checks ----
    if (wid == 0) {
        int c = (lane < NSL) ? sCnt[lane] : 0;
        if (lane < NSL && c > SLCAP) sFlag = 1;       // slice overflow
        int v = c;
        #pragma unroll
        for (int off = 1; off < NSL; off <<= 1) {
            const int o = __shfl(v, lane - off, 64);
            if (lane >= off) v += o;
        }
        if (lane < NSL) sPre[lane] = v - c;           // exclusive prefix
        if (lane == NSL - 1) {
            sHC = v;                                  // total head count
            if (v < NCAND) sFlag = 1;                 // must cover top-128
        }
    }
    __syncthreads();
    int bad = sFlag;

    // ---- P1b: gather slices -> contiguous sHead ----
    if (!bad) {
        const unsigned long long* kr = (const unsigned long long*)((const char*)ws + KEY_OFF)
                                       + (size_t)b * NSL * SLCAP;
        for (int s = wid; s < NSL; s += NWAVES) {
            const int n = sCnt[s], base = sPre[s];
            if (lane < n) sHead[base + lane] = kr[s * SLCAP + lane];
        }
    }
    __syncthreads();

    // ---- P2: rank-scatter -> exact sorted global top-128 ----
    if (!bad) {
        const int hc = sHC;
        if (tid < hc) {
            const unsigned long long k = sHead[tid];
            int r = 0;
            const int hp = (hc + 7) & ~7;
            for (int q = 0; q < hp; q += 8) {     // 8 independent broadcast reads
                #pragma unroll
                for (int u = 0; u < 8; ++u) r += (sHead[q + u] > k) ? 1 : 0;
            }
            if (r < NCAND) sTop[r] = k;
        }
    }
    __syncthreads();

    // ---- P3: candidate prep (fold 16-way bmax here) ----
    if (!bad && tid < NCAND) {
        float mm = sRedF[0];
        #pragma unroll
        for (int q = 1; q < NWAVES; ++q) mm = fmaxf(mm, sRedF[q]);
        const unsigned long long k = sTop[tid];
        const int i = 131071 - (int)(k & 0x1FFFFULL);
        const int bi = i / NC, l = i - bi * NC;
        const float4 sb = sBox[bi];
        const float o = (float)l * (mm + 1.0f);
        float4 ob;
        ob.x = sb.x + o; ob.y = sb.y + o; ob.z = sb.z + o; ob.w = sb.w + o;
        sOB[tid] = ob;
        sOar[tid] = (ob.z - ob.x) * (ob.w - ob.y);
    }
    __syncthreads();

    // ---- P4: suppression bitmap via ballot (128 rows x 2 words) ----
    if (!bad) {
        const int w = wid & 1;                   // column word
        const int r0 = (wid >> 1) << 4;          // 8 groups x 16 rows
        const int cj = (w << 6) + lane;          // this lane's column candidate
        const float4 cb = sOB[cj];
        const float car = sOar[cj];
        for (int t = 0; t < 16; ++t) {
            const int i = r0 + t;
            const float4 rb = sOB[i];            // broadcast
            const float ra = sOar[i];
            float iw = fminf(rb.z, cb.z) - fmaxf(rb.x, cb.x);
            float ih = fminf(rb.w, cb.w) - fmaxf(rb.y, cb.y);
            iw = fmaxf(iw, 0.f); ih = fmaxf(ih, 0.f);
            const float inter = iw * ih;
            const bool sup = inter > IOU_THR * (ra + car - inter);
            const unsigned long long bits = __ballot(sup);
            if (lane == 0) sSup[(i << 1) | w] = bits;   // row i suppresses word w
        }
    }
    __syncthreads();

    // ---- P5: bitmap scan (wave 0): per-step chain is register-only ----
    if (!bad && wid == 0) {
        unsigned long long live = (lane < 2) ? ~0ULL : 0ULL;   // C == 128
        unsigned long long keepW = 0ULL;
        int kept = 0;
        const int myw = lane & 1;
        for (int ch = 0; ch < 2 && kept < TOPK; ++ch) {
            unsigned long long cur = __shfl(live, ch, 64);  // word ch, replicated
            unsigned long long acc = 0ULL;
            #pragma unroll 8
            for (int bit = 0; bit < 64; ++bit) {
                const int i = (ch << 6) | bit;
                const unsigned long long rowC = sSup[(i << 1) | ch];
                const unsigned long long rowM = sSup[(i << 1) | myw];
                if ((cur >> bit) & 1ULL) {                  // wave-uniform
                    cur &= ~rowC;
                    acc |= rowM;
                    if (lane == ch) keepW |= 1ULL << bit;
                }
            }
            if (lane < 2) live &= ~acc;
            int c = __popcll(keepW);
            for (int off = 32; off >= 1; off >>= 1) c += __shfl_xor(c, off, 64);
            kept = c;
        }
        if (lane < 2) sKeepW[lane] = keepW;
        if (lane == 0) sNK = kept;
    }
    __syncthreads();
    if (tid == 0 && sFlag == 0) {
        if (sNK < TOPK) sFlag = 1; else sKept = TOPK;   // <100 survivors -> exact path
    }
    __syncthreads();
    bad = sFlag;

    // ---- P6: rank -> direct outputs ----
    if (!bad && tid < NCAND) {
        const int w = tid >> 6;
        const unsigned long long m = sKeepW[w];
        if ((m >> (tid & 63)) & 1ULL) {
            int rank = __popcll(m & ((1ULL << (tid & 63)) - 1ULL));
            if (w) rank += __popcll(sKeepW[0]);
            if (rank < TOPK) {
                const unsigned long long k = sTop[tid];
                const int i = 131071 - (int)(k & 0x1FFFFULL);
                const int bi = i / NC, l = i - bi * NC;
                const float4 sb = sBox[bi];
                const float z = inv_mono((unsigned int)(k >> 17));
                const int oi = b * TOPK + rank;
                out[oi] = 1.0f / (1.0f + expf(-z));
                out[BS * TOPK + oi] = (float)l;
                out[2 * BS * TOPK + oi * 4 + 0] = sb.x;
                out[2 * BS * TOPK + oi * 4 + 1] = sb.y;
                out[2 * BS * TOPK + oi * 4 + 2] = sb.z;
                out[2 * BS * TOPK + oi * 4 + 3] = sb.w;
            }
        }
    }

    if (bad) {
        // ======== exact fallback (never taken for sane inputs) ========
        unsigned long long lo = 0, hi = (1ULL << 49) - 1;
        while (lo < hi) {
            const unsigned long long mid = lo + ((hi - lo + 1) >> 1);
            int c = 0;
            for (int j = tid; j < NF4; j += NT) {
                const float4 v = ((const float4*)lg)[j];
                const float zv[4] = { v.x, v.y, v.z, v.w };
                #pragma unroll
                for (int q = 0; q < 4; ++q)
                    c += (make_key(mono_u(zv[q]), 4 * j + q) >= mid) ? 1 : 0;
            }
            for (int off = 32; off >= 1; off >>= 1) c += __shfl_xor(c, off, 64);
            if (lane == 0) sWTot[wid] = c;
            __syncthreads();
            if (tid == 0) {
                int a = 0;
                for (int w = 0; w < NWAVES; ++w) a += sWTot[w];
                sPos = a;
            }
            __syncthreads();
            if (sPos >= PRE_TOPK) lo = mid; else hi = mid - 1;
            __syncthreads();
        }
        if (tid == 0) sPos = 0;
        __syncthreads();
        for (int j = tid; j < NF4; j += NT) {
            const float4 v = ((const float4*)lg)[j];
            const float zv[4] = { v.x, v.y, v.z, v.w };
            #pragma unroll
            for (int q = 0; q < 4; ++q) {
                const unsigned long long k = make_key(mono_u(zv[q]), 4 * j + q);
                const bool cand = k >= lo;        // exactly 10000 (keys distinct)
                const unsigned long long mask = __ballot(cand);
                int pos = 0;
                if (lane == 0 && mask) pos = atomicAdd(&sPos, __popcll(mask));
                pos = __shfl(pos, 0, 64);
                if (cand) sPool[pos + __popcll(mask & laneLT)] = k;
            }
        }
        __syncthreads();
        {   // full rank sort of 10000 (slow, correct)
            unsigned long long stash[10]; int spp[10]; int ns = 0;
            for (int p = tid; p < PRE_TOPK; p += NT) {
                const unsigned long long k = sPool[p];
                int r = 0;
                for (int q = 0; q < PRE_TOPK; ++q) r += (sPool[q] > k) ? 1 : 0;
                if (ns < 10) { stash[ns] = k; spp[ns] = r; ++ns; }
            }
            __syncthreads();
            for (int q = 0; q < ns; ++q) sPool[spp[q]] = stash[q];
        }
        __syncthreads();
        float lmax = -3.4e38f;
        for (int p = tid; p < PRE_TOPK; p += NT) {
            const int i = 131071 - (int)(sPool[p] & 0x1FFFFULL);
            const float4 sb = sBox[i / NC];
            lmax = fmaxf(lmax, fmaxf(fmaxf(sb.x, sb.y), fmaxf(sb.z, sb.w)));
        }
        for (int off = 32; off >= 1; off >>= 1)
            lmax = fmaxf(lmax, __shfl_xor(lmax, off, 64));
        if (lane == 0) sRedF[wid] = lmax;
        __syncthreads();
        if (tid == 0) {
            float mm = sRedF[0];
            for (int k2 = 1; k2 < NWAVES; ++k2) mm = fmaxf(mm, sRedF[k2]);
            sBmax = mm;
        }
        __syncthreads();
        const float offc = sBmax + 1.0f;
        if (wid == 0) {
            int kept = 0;
            for (int base = 0; base < PRE_TOPK && kept < TOPK; base += 64) {
                const int c = base + lane;
                const bool valid = c < PRE_TOPK;
                const unsigned long long k = valid ? sPool[c] : 0ULL;
                const int i = valid ? (131071 - (int)(k & 0x1FFFFULL)) : 0;
                const int bi = i / NC, l = i - bi * NC;
                const float4 sb = sBox[bi];
                const float o = (float)l * offc;
                const float ox1 = sb.x + o, oy1 = sb.y + o, ox2 = sb.z + o, oy2 = sb.w + o;
                const float ar = (ox2 - ox1) * (oy2 - oy1);
                bool alive = valid;
                for (int jj = 0; jj < kept; ++jj) {
                    float iw = fminf(sKx2[jj], ox2) - fmaxf(sKx1[jj], ox1);
                    float ih = fminf(sKy2[jj], oy2) - fmaxf(sKy1[jj], oy1);
                    iw = fmaxf(iw, 0.f); ih = fmaxf(ih, 0.f);
                    const float inter = iw * ih;
                    if (inter > IOU_THR * (sKa[jj] + ar - inter)) alive = false;
                }
                unsigned long long mask = __ballot(alive);
                while (mask != 0ULL && kept < TOPK) {
                    const int s = __ffsll((unsigned long long)mask) - 1;
                    const float px1 = __shfl(ox1, s, 64);
                    const float py1 = __shfl(oy1, s, 64);
                    const float px2 = __shfl(ox2, s, 64);
                    const float py2 = __shfl(oy2, s, 64);
                    const float pa  = __shfl(ar,  s, 64);
                    if (lane == s) {
                        sKx1[kept] = ox1; sKy1[kept] = oy1; sKx2[kept] = ox2;
                        sKy2[kept] = oy2; sKa[kept] = ar;
                        const int oi = b * TOPK + kept;
                        const float z = inv_mono((unsigned int)(k >> 17));
                        const float sc = 1.0f / (1.0f + expf(-z));
                        out[oi] = sc;
                        out[BS * TOPK + oi] = (float)l;
                        out[2 * BS * TOPK + oi * 4 + 0] = sb.x;
                        out[2 * BS * TOPK + oi * 4 + 1] = sb.y;
                        out[2 * BS * TOPK + oi * 4 + 2] = sb.z;
                        out[2 * BS * TOPK + oi * 4 + 3] = sb.w;
                        if (kept == 0) { sFirst[0] = sc; sFirst[1] = (float)l;
                                         sFirst[2] = sb.x; sFirst[3] = sb.y;
                                         sFirst[4] = sb.z; sFirst[5] = sb.w; }
                    }
                    ++kept;
                    if (alive) {
                        float iw = fminf(px2, ox2) - fmaxf(px1, ox1);
                        float ih = fminf(py2, oy2) - fmaxf(py1, oy1);
                        iw = fmaxf(iw, 0.f); ih = fmaxf(ih, 0.f);
                        const float inter = iw * ih;
                        if (inter > IOU_THR * (pa + ar - inter)) alive = false;
                    }
                    mask = __ballot(alive);
                }
            }
            if (lane == 0) sKept = kept;
        }
        __syncthreads();
    }

    // exhaustion: ref's argmax over all -inf -> index 0 -> replicate row 0
    for (int t = sKept + tid; t < TOPK; t += NT) {
        const int oi = b * TOPK + t;
        out[oi] = sFirst[0];
        out[BS * TOPK + oi] = sFirst[1];
        out[2 * BS * TOPK + oi * 4 + 0] = sFirst[2];
        out[2 * BS * TOPK + oi * 4 + 1] = sFirst[3];
        out[2 * BS * TOPK + oi * 4 + 2] = sFirst[4];
        out[2 * BS * TOPK + oi * 4 + 3] = sFirst[5];
    }
}

extern "C" void kernel_launch(void* const* d_in, const int* in_sizes, int n_in,
                              void* d_out, int out_size, void* d_ws, size_t ws_size,
                              hipStream_t stream) {
    const float* logits = (const float*)d_in[0];   // (8, 900, 91) fp32
    const float* pboxes = (const float*)d_in[1];   // (8, 900, 4) fp32
    const float* ts     = (const float*)d_in[2];   // (8, 2) fp32
    if (ws_size >= WS_REQ) {
        hipLaunchKernelGGL(k_sweep, dim3(NSL, BS), dim3(K1T), 0, stream,
                           logits, d_ws);
        hipLaunchKernelGGL(k_tail, dim3(BS), dim3(NT), 0, stream,
                           logits, pboxes, ts, (float*)d_out, d_ws, 0);
    } else {
        // no workspace: exact in-kernel fallback path (slow, correct)
        hipLaunchKernelGGL(k_tail, dim3(BS), dim3(NT), 0, stream,
                           logits, pboxes, ts, (float*)d_out, d_ws, 1);
    }
}